// Round 8
// baseline (2354.366 us; speedup 1.0000x reference)
//
#include <hip/hip_runtime.h>
#include <hip/hip_bf16.h>

#define BB 256
#define TT 128
#define NN 1024
#define HH 1024
#define G4 4096

typedef __attribute__((ext_vector_type(4))) float f32x4;
typedef __attribute__((ext_vector_type(8))) short bf16x8;

__device__ __forceinline__ unsigned short f2bf(float f) {
    unsigned int u = __builtin_bit_cast(unsigned int, f);
    u += 0x7FFFu + ((u >> 16) & 1u);
    return (unsigned short)(u >> 16);
}
__device__ __forceinline__ float bf2f(unsigned short s) {
    unsigned int u = ((unsigned int)s) << 16;
    return __builtin_bit_cast(float, u);
}

// ---------------------------------------------------------------------------
// K1: attention weights (time-invariant) + input_weighted (f32) + w_in bf16
// ---------------------------------------------------------------------------
__global__ __launch_bounds__(512) void k_attn(
    const float* __restrict__ x, const float* __restrict__ attn_w,
    const float* __restrict__ attn_b, float* __restrict__ out0,
    unsigned short* __restrict__ win_bf)
{
    const int b = blockIdx.x;
    const int tid = threadIdx.x;
    const float* xb = x + (size_t)b * (TT * NN);
    const float* wx = attn_w + 2 * HH;

    float s0 = 0.f, s1 = 0.f;
    for (int t = 0; t < TT; ++t) {
        float2 v = *(const float2*)(xb + (size_t)t * NN + tid * 2);
        float w = wx[t];
        s0 += v.x * w; s1 += v.y * w;
    }
    float ab = attn_b[0];
    s0 += ab; s1 += ab;

    __shared__ float red[8];
    const int wv = tid >> 6, ln = tid & 63;
    float m = fmaxf(s0, s1);
#pragma unroll
    for (int off = 32; off > 0; off >>= 1) m = fmaxf(m, __shfl_xor(m, off));
    if (ln == 0) red[wv] = m;
    __syncthreads();
    m = red[0];
#pragma unroll
    for (int i = 1; i < 8; ++i) m = fmaxf(m, red[i]);

    float e0 = expf(s0 - m), e1 = expf(s1 - m);
    float sum = e0 + e1;
#pragma unroll
    for (int off = 32; off > 0; off >>= 1) sum += __shfl_xor(sum, off);
    __syncthreads();
    if (ln == 0) red[wv] = sum;
    __syncthreads();
    sum = 0.f;
#pragma unroll
    for (int i = 0; i < 8; ++i) sum += red[i];
    const float inv = 1.0f / sum;
    const float a0 = e0 * inv, a1 = e1 * inv;

    float* o = out0 + (size_t)b * (TT * NN);
    unsigned short* wb = win_bf + (size_t)b * (TT * NN);
    for (int t = 0; t < TT; ++t) {
        float2 v = *(const float2*)(xb + (size_t)t * NN + tid * 2);
        float2 w; w.x = a0 * v.x; w.y = a1 * v.y;
        *(float2*)(o + (size_t)t * NN + tid * 2) = w;
        unsigned int pk = (unsigned int)f2bf(w.x) | ((unsigned int)f2bf(w.y) << 16);
        *(unsigned int*)(wb + (size_t)t * NN + tid * 2) = pk;
    }
}

// ---------------------------------------------------------------------------
// K2: convert W_ih / W_hh to bf16 with gate-interleaved row perm p=j*4+g
// ---------------------------------------------------------------------------
__global__ __launch_bounds__(256) void k_prep_w(
    const float* __restrict__ Wih, const float* __restrict__ Whh,
    const float* __restrict__ bih, const float* __restrict__ bhh,
    unsigned short* __restrict__ WihP, unsigned short* __restrict__ WhhP,
    float* __restrict__ biasP)
{
    const int p = blockIdx.x;
    const int j = p >> 2, g = p & 3;
    const int r = g * HH + j;
    const int tid = threadIdx.x;
    {
        float4 v = *(const float4*)(Wih + (size_t)r * NN + tid * 4);
        ushort4 o;
        o.x = f2bf(v.x); o.y = f2bf(v.y); o.z = f2bf(v.z); o.w = f2bf(v.w);
        *(ushort4*)(WihP + (size_t)p * NN + tid * 4) = o;
    }
    {
        float4 v = *(const float4*)(Whh + (size_t)r * HH + tid * 4);
        ushort4 o;
        o.x = f2bf(v.x); o.y = f2bf(v.y); o.z = f2bf(v.z); o.w = f2bf(v.w);
        *(ushort4*)(WhhP + (size_t)p * HH + tid * 4) = o;
    }
    if (tid == 0) biasP[p] = bih[r] + bhh[r];
}

// ---------------------------------------------------------------------------
// K3: Xp = w_in_bf16 (32768,1024) @ WihP^T (4096,1024) -> bf16 (32768,4096)
// ---------------------------------------------------------------------------
__global__ __launch_bounds__(256) void k_gemm_xp(
    const unsigned short* __restrict__ A,
    const unsigned short* __restrict__ Bm,
    unsigned short* __restrict__ C)
{
    __shared__ unsigned short lA[128 * 32];
    __shared__ unsigned short lB[128 * 32];

    const int bid = blockIdx.x;
    const int cpx = gridDim.x >> 3;
    const int swz = (bid & 7) * cpx + (bid >> 3);
    const int NTN = G4 / 128;
    const int tm = swz / NTN, tn = swz % NTN;

    const int tid = threadIdx.x;
    const int wv = tid >> 6, ln = tid & 63;
    const int wr = wv >> 1, wc = wv & 1;

    f32x4 acc[4][4] = {};

    const unsigned short* Ag = A + (size_t)tm * 128 * NN;
    const unsigned short* Bg = Bm + (size_t)tn * 128 * NN;
    const int srow = ln >> 2;
    const int sseg = ln & 3;

    for (int k0 = 0; k0 < NN; k0 += 32) {
        __syncthreads();
#pragma unroll
        for (int q = 0; q < 2; ++q) {
            const int row = wv * 32 + q * 16 + srow;
            __builtin_amdgcn_global_load_lds(
                (const __attribute__((address_space(1))) void*)(Ag + (size_t)row * NN + k0 + sseg * 8),
                (__attribute__((address_space(3))) void*)(&lA[(wv * 32 + q * 16) * 32]),
                16, 0, 0);
            __builtin_amdgcn_global_load_lds(
                (const __attribute__((address_space(1))) void*)(Bg + (size_t)row * NN + k0 + sseg * 8),
                (__attribute__((address_space(3))) void*)(&lB[(wv * 32 + q * 16) * 32]),
                16, 0, 0);
        }
        __syncthreads();

        const int rlo = ln & 15, khi = ln >> 4;
        bf16x8 af[4], bfr[4];
#pragma unroll
        for (int m = 0; m < 4; ++m)
            af[m] = *(const bf16x8*)&lA[(wr * 64 + m * 16 + rlo) * 32 + khi * 8];
#pragma unroll
        for (int n = 0; n < 4; ++n)
            bfr[n] = *(const bf16x8*)&lB[(wc * 64 + n * 16 + rlo) * 32 + khi * 8];
#pragma unroll
        for (int m = 0; m < 4; ++m)
#pragma unroll
            for (int n = 0; n < 4; ++n)
                acc[m][n] = __builtin_amdgcn_mfma_f32_16x16x32_bf16(af[m], bfr[n], acc[m][n], 0, 0, 0);
    }

    const int rlo = ln & 15, rhi = ln >> 4;
#pragma unroll
    for (int m = 0; m < 4; ++m)
#pragma unroll
        for (int n = 0; n < 4; ++n)
#pragma unroll
            for (int j = 0; j < 4; ++j) {
                const int row = tm * 128 + wr * 64 + m * 16 + rhi * 4 + j;
                const int col = tn * 128 + wc * 64 + n * 16 + rlo;
                C[(size_t)row * G4 + col] = f2bf(acc[m][n][j]);
            }
}

// ---------------------------------------------------------------------------
// K4 v5 (per step): ONE barrier per step, no spills.
//   256 blocks x 512 threads (8 waves, launch_bounds(512,1) -> full VGPRs).
//   B (W_hh slice, 128 KiB) -> LDS once via global_load_lds with
//   pre-swizzled SOURCE (k_recur2 STAGE, proven; zero VGPR cost).
//   A (h) global -> registers, 16-chunk unroll (k_step4 LOADA, proven).
//   Single vmcnt(0) + s_barrier, then 16 chunks of 4 ds_read_b128 + 4 MFMA.
//   Epilogue = verified butterfly + LSTM pointwise.
// ---------------------------------------------------------------------------
__global__ __launch_bounds__(512, 1) void k_step5(
    const int t,
    const unsigned short* __restrict__ hbf,
    const unsigned short* __restrict__ WhhP,
    const unsigned short* __restrict__ Xp,
    const float* __restrict__ biasP,
    float* __restrict__ cbuf,
    unsigned short* __restrict__ hbf_out,
    float* __restrict__ out1)
{
    __shared__ unsigned short lB[64 * 1024];   // 128 KiB, swizzled layout

    const int bid = blockIdx.x;
    const int ti = bid >> 6, tj = bid & 63;
    const int tid = threadIdx.x;
    const int wv = tid >> 6, ln = tid & 63;
    const int wr = wv >> 1, wc = wv & 1;
    const int rlo = ln & 15, khi = ln >> 4;
    const int khi16 = khi * 16;

    const char* Ab = (const char*)hbf + (size_t)(ti * 64) * 2048;
    const char* Bb = (const char*)WhhP + (size_t)(tj * 64) * 2048;

    // ---- B stage: 16 gload_lds/thread, pre-swizzled source (k_recur2) ----
#pragma unroll
    for (int q = 0; q < 16; ++q) {
        const int i = wv * 16 + q;             // 0..127, 1 KiB each
        const int r = i >> 1, half = i & 1;
        const int lbo = (half * 1024 + ln * 16) ^ ((r & 7) << 4);
        __builtin_amdgcn_global_load_lds(
            (const __attribute__((address_space(1))) void*)(Bb + (size_t)r * 2048 + lbo),
            (__attribute__((address_space(3))) void*)((char*)lB + i * 1024),
            16, 0, 0);
    }

    // ---- A chunk loads 0..15 -> regs (k_step4, proven) ----
    const char* abase = Ab + (size_t)(wr * 16 + rlo) * 2048 + khi16;
#define LOADA(c) \
    const bf16x8 a0_##c = *(const bf16x8*)(abase + (c) * 128); \
    const bf16x8 a1_##c = *(const bf16x8*)(abase + (c) * 128 + 64);
    LOADA(0) LOADA(1) LOADA(2) LOADA(3) LOADA(4) LOADA(5) LOADA(6) LOADA(7)
    LOADA(8) LOADA(9) LOADA(10) LOADA(11) LOADA(12) LOADA(13) LOADA(14) LOADA(15)
#undef LOADA

    // ---- epilogue coords + data (k_step4, proven) ----
    const int r_loc = wr * 16 + ((ln >> 4) << 2) + (ln & 3);
    const int u_loc0 = wc * 8 + ((ln & 15) >> 2);
    const int bg = ti * 64 + r_loc;

    ushort4 xp4[2];
    float cp[2];
    float4 bias4[2];
#pragma unroll
    for (int n = 0; n < 2; ++n) {
        xp4[n] = *(const ushort4*)((const char*)Xp +
                    ((size_t)bg * TT + t) * 8192 + tj * 128 + (u_loc0 + n * 4) * 8);
        cp[n] = cbuf[(size_t)bg * HH + tj * 16 + u_loc0 + n * 4];
        bias4[n] = *(const float4*)&biasP[(tj * 16 + u_loc0 + n * 4) * 4];
    }

    // ---- single drain + barrier: everything resident ----
    asm volatile("s_waitcnt vmcnt(0)" ::: "memory");
    __builtin_amdgcn_s_barrier();
    __builtin_amdgcn_sched_barrier(0);

    // ---- B read bases (k_step4, proven) ----
    const int brow0 = wc * 32 + rlo;
    const int bswz = (brow0 & 7) << 4;
    const char* lb0 = (const char*)lB + (size_t)brow0 * 2048;
    const char* lb1 = lb0 + 16 * 2048;
    const int okk0 = khi16 ^ bswz;
    const int okk1 = (64 + khi16) ^ bswz;

    f32x4 acc[2] = {};

#define CHUNK(c) do { \
    const bf16x8 b00 = *(const bf16x8*)(lb0 + (c) * 128 + okk0); \
    const bf16x8 b01 = *(const bf16x8*)(lb0 + (c) * 128 + okk1); \
    const bf16x8 b10 = *(const bf16x8*)(lb1 + (c) * 128 + okk0); \
    const bf16x8 b11 = *(const bf16x8*)(lb1 + (c) * 128 + okk1); \
    acc[0] = __builtin_amdgcn_mfma_f32_16x16x32_bf16(a0_##c, b00, acc[0], 0, 0, 0); \
    acc[1] = __builtin_amdgcn_mfma_f32_16x16x32_bf16(a0_##c, b10, acc[1], 0, 0, 0); \
    acc[0] = __builtin_amdgcn_mfma_f32_16x16x32_bf16(a1_##c, b01, acc[0], 0, 0, 0); \
    acc[1] = __builtin_amdgcn_mfma_f32_16x16x32_bf16(a1_##c, b11, acc[1], 0, 0, 0); \
} while (0)

    CHUNK(0); CHUNK(1); CHUNK(2); CHUNK(3);
    CHUNK(4); CHUNK(5); CHUNK(6); CHUNK(7);
    CHUNK(8); CHUNK(9); CHUNK(10); CHUNK(11);
    CHUNK(12); CHUNK(13); CHUNK(14); CHUNK(15);
#undef CHUNK

    // ---- gate transpose (verified butterfly) + LSTM pointwise ----
#pragma unroll
    for (int n = 0; n < 2; ++n) {
        f32x4 v = acc[n], u, w;
#pragma unroll
        for (int k = 0; k < 4; ++k) {
            float s = __shfl_xor(v[k ^ 1], 1);
            u[k] = ((k & 1) == (ln & 1)) ? v[k] : s;
        }
#pragma unroll
        for (int k = 0; k < 4; ++k) {
            float s = __shfl_xor(u[k ^ 2], 2);
            w[k] = (((k >> 1) & 1) == ((ln >> 1) & 1)) ? u[k] : s;
        }
        const float gi = w[0] + bf2f(xp4[n].x) + bias4[n].x;
        const float gf = w[1] + bf2f(xp4[n].y) + bias4[n].y;
        const float gg = w[2] + bf2f(xp4[n].z) + bias4[n].z;
        const float go = w[3] + bf2f(xp4[n].w) + bias4[n].w;
        const float i_ = 1.f / (1.f + expf(-gi));
        const float f_ = 1.f / (1.f + expf(-gf));
        const float g_ = tanhf(gg);
        const float o_ = 1.f / (1.f + expf(-go));
        const float cc = f_ * cp[n] + i_ * g_;
        const float h_ = o_ * tanhf(cc);
        const int ug = tj * 16 + u_loc0 + n * 4;
        cbuf[(size_t)bg * HH + ug] = cc;
        out1[(size_t)bg * (TT * HH) + (size_t)t * HH + ug] = h_;
        hbf_out[(size_t)bg * HH + ug] = f2bf(h_);
    }
}

// zero-init: clears hbf0|hbf1|cbuf (2 MiB contiguous)
__global__ __launch_bounds__(256) void k_zero(float4* __restrict__ p)
{
    p[blockIdx.x * 256 + threadIdx.x] = make_float4(0.f, 0.f, 0.f, 0.f);
}

extern "C" void kernel_launch(void* const* d_in, const int* in_sizes, int n_in,
                              void* d_out, int out_size, void* d_ws, size_t ws_size,
                              hipStream_t stream)
{
    const float* x      = (const float*)d_in[0];
    const float* Wih    = (const float*)d_in[1];
    const float* Whh    = (const float*)d_in[2];
    const float* bih    = (const float*)d_in[3];
    const float* bhh    = (const float*)d_in[4];
    const float* attn_w = (const float*)d_in[5];
    const float* attn_b = (const float*)d_in[6];

    float* out0 = (float*)d_out;                               // (B,T,N)
    float* out1 = (float*)d_out + (size_t)BB * TT * NN;        // (B,T,H)

    char* w = (char*)d_ws;
    unsigned short* WihP  = (unsigned short*)(w);                       //  8 MiB
    unsigned short* WhhP  = (unsigned short*)(w + 8388608);             //  8 MiB
    float*          biasP = (float*)(w + 16777216);                     // 16 KiB
    unsigned short* winbf = (unsigned short*)(w + 16793600);            // 64 MiB
    unsigned short* Xp    = (unsigned short*)(w + 83902464);            // 256 MiB
    unsigned short* hbf0  = (unsigned short*)(w + 352337920);           // 512 KiB
    unsigned short* hbf1  = (unsigned short*)(w + 352862208);           // 512 KiB
    float*          cbuf  = (float*)(w + 353386496);                    //   1 MiB

    k_attn<<<BB, 512, 0, stream>>>(x, attn_w, attn_b, out0, winbf);
    k_prep_w<<<G4, 256, 0, stream>>>(Wih, Whh, bih, bhh, WihP, WhhP, biasP);
    k_gemm_xp<<<(BB * TT / 128) * (G4 / 128), 256, 0, stream>>>(winbf, WihP, Xp);
    k_zero<<<512, 256, 0, stream>>>((float4*)hbf0);   // h(t=0)=0, c=0

    for (int t = 0; t < TT; ++t) {
        const unsigned short* hin = (t & 1) ? hbf1 : hbf0;
        unsigned short* hout      = (t & 1) ? hbf0 : hbf1;
        k_step5<<<256, 512, 0, stream>>>(t, hin, WhhP, Xp, biasP, cbuf, hout, out1);
    }
}

// Round 10
// 1831.707 us; speedup vs baseline: 1.2853x; 1.2853x over previous
//
#include <hip/hip_runtime.h>
#include <hip/hip_bf16.h>

#define BB 256
#define TT 128
#define NN 1024
#define HH 1024
#define G4 4096

typedef __attribute__((ext_vector_type(4))) float f32x4;
typedef __attribute__((ext_vector_type(8))) short bf16x8;

__device__ __forceinline__ unsigned short f2bf(float f) {
    unsigned int u = __builtin_bit_cast(unsigned int, f);
    u += 0x7FFFu + ((u >> 16) & 1u);
    return (unsigned short)(u >> 16);
}
__device__ __forceinline__ float bf2f(unsigned short s) {
    unsigned int u = ((unsigned int)s) << 16;
    return __builtin_bit_cast(float, u);
}

// ---------------------------------------------------------------------------
// K1: attention weights (time-invariant) + input_weighted (f32) + w_in bf16
// ---------------------------------------------------------------------------
__global__ __launch_bounds__(512) void k_attn(
    const float* __restrict__ x, const float* __restrict__ attn_w,
    const float* __restrict__ attn_b, float* __restrict__ out0,
    unsigned short* __restrict__ win_bf)
{
    const int b = blockIdx.x;
    const int tid = threadIdx.x;
    const float* xb = x + (size_t)b * (TT * NN);
    const float* wx = attn_w + 2 * HH;

    float s0 = 0.f, s1 = 0.f;
    for (int t = 0; t < TT; ++t) {
        float2 v = *(const float2*)(xb + (size_t)t * NN + tid * 2);
        float w = wx[t];
        s0 += v.x * w; s1 += v.y * w;
    }
    float ab = attn_b[0];
    s0 += ab; s1 += ab;

    __shared__ float red[8];
    const int wv = tid >> 6, ln = tid & 63;
    float m = fmaxf(s0, s1);
#pragma unroll
    for (int off = 32; off > 0; off >>= 1) m = fmaxf(m, __shfl_xor(m, off));
    if (ln == 0) red[wv] = m;
    __syncthreads();
    m = red[0];
#pragma unroll
    for (int i = 1; i < 8; ++i) m = fmaxf(m, red[i]);

    float e0 = expf(s0 - m), e1 = expf(s1 - m);
    float sum = e0 + e1;
#pragma unroll
    for (int off = 32; off > 0; off >>= 1) sum += __shfl_xor(sum, off);
    __syncthreads();
    if (ln == 0) red[wv] = sum;
    __syncthreads();
    sum = 0.f;
#pragma unroll
    for (int i = 0; i < 8; ++i) sum += red[i];
    const float inv = 1.0f / sum;
    const float a0 = e0 * inv, a1 = e1 * inv;

    float* o = out0 + (size_t)b * (TT * NN);
    unsigned short* wb = win_bf + (size_t)b * (TT * NN);
    for (int t = 0; t < TT; ++t) {
        float2 v = *(const float2*)(xb + (size_t)t * NN + tid * 2);
        float2 w; w.x = a0 * v.x; w.y = a1 * v.y;
        *(float2*)(o + (size_t)t * NN + tid * 2) = w;
        unsigned int pk = (unsigned int)f2bf(w.x) | ((unsigned int)f2bf(w.y) << 16);
        *(unsigned int*)(wb + (size_t)t * NN + tid * 2) = pk;
    }
}

// ---------------------------------------------------------------------------
// K2: convert W_ih / W_hh to bf16 with gate-interleaved row perm p=j*4+g
// ---------------------------------------------------------------------------
__global__ __launch_bounds__(256) void k_prep_w(
    const float* __restrict__ Wih, const float* __restrict__ Whh,
    const float* __restrict__ bih, const float* __restrict__ bhh,
    unsigned short* __restrict__ WihP, unsigned short* __restrict__ WhhP,
    float* __restrict__ biasP)
{
    const int p = blockIdx.x;
    const int j = p >> 2, g = p & 3;
    const int r = g * HH + j;
    const int tid = threadIdx.x;
    {
        float4 v = *(const float4*)(Wih + (size_t)r * NN + tid * 4);
        ushort4 o;
        o.x = f2bf(v.x); o.y = f2bf(v.y); o.z = f2bf(v.z); o.w = f2bf(v.w);
        *(ushort4*)(WihP + (size_t)p * NN + tid * 4) = o;
    }
    {
        float4 v = *(const float4*)(Whh + (size_t)r * HH + tid * 4);
        ushort4 o;
        o.x = f2bf(v.x); o.y = f2bf(v.y); o.z = f2bf(v.z); o.w = f2bf(v.w);
        *(ushort4*)(WhhP + (size_t)p * HH + tid * 4) = o;
    }
    if (tid == 0) biasP[p] = bih[r] + bhh[r];
}

// ---------------------------------------------------------------------------
// K3 v2: Xp = winbf (32768,1024) @ WihP^T (4096,1024) -> bf16 (32768,4096)
//   256x256 tile, BK=32, 512 threads (8 waves 2x4, wave = 128x64 out).
//   3-buffer LDS rotation + counted vmcnt(8/4/0)  [k_step3-proven ledger].
//   kslice-major LDS layout [khi][row][8elem]; STAGE now uses WAVE-UNIFORM
//   dest + permuted per-lane source (rule: gload_lds dest = base + lane*16).
//   setprio(1) around the 32-MFMA cluster. XCD-swizzled grid (2048 blocks).
// ---------------------------------------------------------------------------
__global__ __launch_bounds__(512, 1) void k_gemm_xp2(
    const unsigned short* __restrict__ A,
    const unsigned short* __restrict__ Bm,
    unsigned short* __restrict__ C)
{
    __shared__ unsigned short lA[3][4][256][8];   // 48 KiB: [buf][khi][row][8]
    __shared__ unsigned short lB[3][4][256][8];   // 48 KiB

    const int bid = blockIdx.x;
    const int cpx = gridDim.x >> 3;               // 2048/8 = 256 (bijective)
    const int swz = (bid & 7) * cpx + (bid >> 3);
    const int NTN = G4 / 256;                     // 16
    const int tm = swz / NTN, tn = swz % NTN;

    const int tid = threadIdx.x;
    const int wv = tid >> 6, ln = tid & 63;
    const int wm = wv >> 2, wn = wv & 3;          // 2 x 4 wave grid
    const int rlo = ln & 15, khi = ln >> 4;

    const char* Ag = (const char*)A + (size_t)(tm * 256) * 2048;
    const char* Bg = (const char*)Bm + (size_t)(tn * 256) * 2048;

    // staging: wave wv, instr j covers linear slots seg = (wv*2+j)*64 + ln.
    // LDS layout [khi][row][8]: byte offset seg*16 == khi*4096 + row*16 with
    // khi = seg>>8, row = seg&255. Dest is WAVE-UNIFORM base (+lane*16 by HW);
    // source fetches the (khi,row) element this lane's slot must hold.
#define STAGE(buf_, c_) do { \
    _Pragma("unroll") \
    for (int j_ = 0; j_ < 2; ++j_) { \
        const int seg_ = (wv * 2 + j_) * 64 + ln; \
        const int khi_ = seg_ >> 8, row_ = seg_ & 255; \
        __builtin_amdgcn_global_load_lds( \
            (const __attribute__((address_space(1))) void*)(Ag + (size_t)row_ * 2048 + (c_) * 64 + khi_ * 16), \
            (__attribute__((address_space(3))) void*)((char*)&lA[buf_][0][0][0] + (wv * 2 + j_) * 1024), \
            16, 0, 0); \
        __builtin_amdgcn_global_load_lds( \
            (const __attribute__((address_space(1))) void*)(Bg + (size_t)row_ * 2048 + (c_) * 64 + khi_ * 16), \
            (__attribute__((address_space(3))) void*)((char*)&lB[buf_][0][0][0] + (wv * 2 + j_) * 1024), \
            16, 0, 0); \
    } } while (0)

    STAGE(0, 0); STAGE(1, 1); STAGE(2, 2);        // 12 loads/thread in flight

    f32x4 acc[8][4] = {};

    for (int c = 0; c < 32; ++c) {
        const int buf = c % 3;
        if (c < 30)       { asm volatile("s_waitcnt vmcnt(8)" ::: "memory"); }
        else if (c == 30) { asm volatile("s_waitcnt vmcnt(4)" ::: "memory"); }
        else              { asm volatile("s_waitcnt vmcnt(0)" ::: "memory"); }
        __builtin_amdgcn_s_barrier();             // chunk c resident (all waves)

        bf16x8 af[8], bfr[4];
#pragma unroll
        for (int m = 0; m < 8; ++m)
            af[m] = *(const bf16x8*)&lA[buf][khi][wm * 128 + m * 16 + rlo][0];
#pragma unroll
        for (int n = 0; n < 4; ++n)
            bfr[n] = *(const bf16x8*)&lB[buf][khi][wn * 64 + n * 16 + rlo][0];
        asm volatile("s_waitcnt lgkmcnt(0)" ::: "memory");
        __builtin_amdgcn_sched_barrier(0);
        __builtin_amdgcn_s_barrier();             // all waves done reading buf
        if (c < 29) STAGE(buf, c + 3);            // refill buf (flies under MFMA)

        __builtin_amdgcn_s_setprio(1);
#pragma unroll
        for (int m = 0; m < 8; ++m)
#pragma unroll
            for (int n = 0; n < 4; ++n)
                acc[m][n] = __builtin_amdgcn_mfma_f32_16x16x32_bf16(af[m], bfr[n], acc[m][n], 0, 0, 0);
        __builtin_amdgcn_s_setprio(0);
    }
#undef STAGE

    const int rhi = ln >> 4;
#pragma unroll
    for (int m = 0; m < 8; ++m)
#pragma unroll
        for (int n = 0; n < 4; ++n)
#pragma unroll
            for (int j = 0; j < 4; ++j) {
                const int row = tm * 256 + wm * 128 + m * 16 + rhi * 4 + j;
                const int col = tn * 256 + wn * 64 + n * 16 + rlo;
                C[(size_t)row * G4 + col] = f2bf(acc[m][n][j]);
            }
}

// ---------------------------------------------------------------------------
// K4 v3 (per step) — round-5 proven kernel, verbatim. 512 threads / 8 waves.
// ---------------------------------------------------------------------------
__global__ __launch_bounds__(512) void k_step3(
    const int t,
    const unsigned short* __restrict__ hbf,
    const unsigned short* __restrict__ WhhP,
    const unsigned short* __restrict__ Xp,
    const float* __restrict__ biasP,
    float* __restrict__ cbuf,
    unsigned short* __restrict__ hbf_out,
    float* __restrict__ out1)
{
    __shared__ unsigned short lA[3][64 * 128];   // 3 x 16 KiB
    __shared__ unsigned short lB[3][64 * 128];   // 3 x 16 KiB
    __shared__ unsigned short lXp[64 * 64];      // 8 KiB

    const int bid = blockIdx.x;
    const int ti = bid >> 6, tj = bid & 63;
    const int tid = threadIdx.x;
    const int wv = tid >> 6, ln = tid & 63;      // 8 waves
    const int wr = wv >> 1, wc = wv & 1;         // wr 0..3, wc 0..1
    const int rlo = ln & 15, khi = ln >> 4;

    {
        const size_t bg = (size_t)(ti * 64 + wv * 8 + (ln >> 3));
        __builtin_amdgcn_global_load_lds(
            (const __attribute__((address_space(1))) void*)((const char*)Xp + ((bg * TT + t) << 13) + tj * 128 + (ln & 7) * 16),
            (__attribute__((address_space(3))) void*)((char*)lXp + wv * 1024),
            16, 0, 0);
    }

    const char* Ab = (const char*)hbf + (size_t)(ti * 64) * 2048;
    const char* Bb = (const char*)WhhP + (size_t)(tj * 64) * 2048;

#define STAGE(buf_, c_) do { \
    _Pragma("unroll") \
    for (int q_ = 0; q_ < 2; ++q_) { \
        const int r_ = q_ * 32 + wv * 4 + (ln >> 4); \
        const int so_ = (((ln & 15) ^ (r_ & 7)) << 4); \
        __builtin_amdgcn_global_load_lds( \
            (const __attribute__((address_space(1))) void*)(Ab + (size_t)r_ * 2048 + (c_) * 256 + so_), \
            (__attribute__((address_space(3))) void*)((char*)&lA[buf_][0] + q_ * 8192 + wv * 1024), \
            16, 0, 0); \
        __builtin_amdgcn_global_load_lds( \
            (const __attribute__((address_space(1))) void*)(Bb + (size_t)r_ * 2048 + (c_) * 256 + so_), \
            (__attribute__((address_space(3))) void*)((char*)&lB[buf_][0] + q_ * 8192 + wv * 1024), \
            16, 0, 0); \
    } } while (0)

    STAGE(0, 0);
    STAGE(1, 1);
    STAGE(2, 2);

    float4 bias4[2];
#pragma unroll
    for (int n = 0; n < 2; ++n)
        bias4[n] = *(const float4*)&biasP[(tj * 16 + wc * 8 + n * 4 + ((ln & 15) >> 2)) * 4];

    f32x4 acc[2] = {};

#pragma unroll
    for (int c = 0; c < 8; ++c) {
        const int buf = c % 3;
        if (c < 6)       { asm volatile("s_waitcnt vmcnt(8)" ::: "memory"); }
        else if (c == 6) { asm volatile("s_waitcnt vmcnt(4)" ::: "memory"); }
        else             { asm volatile("s_waitcnt vmcnt(0)" ::: "memory"); }
        __builtin_amdgcn_s_barrier();

        bf16x8 af[4], bfr[4][2];
#pragma unroll
        for (int kk = 0; kk < 4; ++kk) {
            {
                const int row = wr * 16 + rlo;
                const int off = (kk * 64 + khi * 16) ^ ((row & 7) << 4);
                af[kk] = *(const bf16x8*)((const char*)&lA[buf][0] + row * 256 + off);
            }
#pragma unroll
            for (int n = 0; n < 2; ++n) {
                const int row = wc * 32 + n * 16 + rlo;
                const int off = (kk * 64 + khi * 16) ^ ((row & 7) << 4);
                bfr[kk][n] = *(const bf16x8*)((const char*)&lB[buf][0] + row * 256 + off);
            }
        }
        asm volatile("s_waitcnt lgkmcnt(0)" ::: "memory");
        __builtin_amdgcn_sched_barrier(0);
        __builtin_amdgcn_s_barrier();
        if (c < 5) STAGE((c + 3) % 3, c + 3);
#pragma unroll
        for (int kk = 0; kk < 4; ++kk)
#pragma unroll
            for (int n = 0; n < 2; ++n)
                acc[n] = __builtin_amdgcn_mfma_f32_16x16x32_bf16(af[kk], bfr[kk][n], acc[n], 0, 0, 0);
    }
#undef STAGE

#pragma unroll
    for (int n = 0; n < 2; ++n) {
        f32x4 v = acc[n], u, w;
#pragma unroll
        for (int k = 0; k < 4; ++k) {
            float s = __shfl_xor(v[k ^ 1], 1);
            u[k] = ((k & 1) == (ln & 1)) ? v[k] : s;
        }
#pragma unroll
        for (int k = 0; k < 4; ++k) {
            float s = __shfl_xor(u[k ^ 2], 2);
            w[k] = (((k >> 1) & 1) == ((ln >> 1) & 1)) ? u[k] : s;
        }
        const int r_loc = wr * 16 + ((ln >> 4) << 2) + (ln & 3);
        const int u_loc = wc * 8 + n * 4 + ((ln & 15) >> 2);
        const ushort4 xp4 = *(const ushort4*)((const char*)lXp + r_loc * 128 + u_loc * 8);
        const float gi = w[0] + bf2f(xp4.x) + bias4[n].x;
        const float gf = w[1] + bf2f(xp4.y) + bias4[n].y;
        const float gg = w[2] + bf2f(xp4.z) + bias4[n].z;
        const float go = w[3] + bf2f(xp4.w) + bias4[n].w;
        const float i_ = 1.f / (1.f + expf(-gi));
        const float f_ = 1.f / (1.f + expf(-gf));
        const float g_ = tanhf(gg);
        const float o_ = 1.f / (1.f + expf(-go));
        const int bg = ti * 64 + r_loc;
        const int ug = tj * 16 + u_loc;
        const float cprev = cbuf[(size_t)bg * HH + ug];
        const float cc = f_ * cprev + i_ * g_;
        cbuf[(size_t)bg * HH + ug] = cc;
        const float h_ = o_ * tanhf(cc);
        out1[(size_t)bg * (TT * HH) + (size_t)t * HH + ug] = h_;
        hbf_out[(size_t)bg * HH + ug] = f2bf(h_);
    }
}

// zero-init: clears hbf0|hbf1|cbuf (2 MiB contiguous)
__global__ __launch_bounds__(256) void k_zero(float4* __restrict__ p)
{
    p[blockIdx.x * 256 + threadIdx.x] = make_float4(0.f, 0.f, 0.f, 0.f);
}

extern "C" void kernel_launch(void* const* d_in, const int* in_sizes, int n_in,
                              void* d_out, int out_size, void* d_ws, size_t ws_size,
                              hipStream_t stream)
{
    const float* x      = (const float*)d_in[0];
    const float* Wih    = (const float*)d_in[1];
    const float* Whh    = (const float*)d_in[2];
    const float* bih    = (const float*)d_in[3];
    const float* bhh    = (const float*)d_in[4];
    const float* attn_w = (const float*)d_in[5];
    const float* attn_b = (const float*)d_in[6];

    float* out0 = (float*)d_out;                               // (B,T,N)
    float* out1 = (float*)d_out + (size_t)BB * TT * NN;        // (B,T,H)

    char* w = (char*)d_ws;
    unsigned short* WihP  = (unsigned short*)(w);                       //  8 MiB
    unsigned short* WhhP  = (unsigned short*)(w + 8388608);             //  8 MiB
    float*          biasP = (float*)(w + 16777216);                     // 16 KiB
    unsigned short* winbf = (unsigned short*)(w + 16793600);            // 64 MiB
    unsigned short* Xp    = (unsigned short*)(w + 83902464);            // 256 MiB
    unsigned short* hbf0  = (unsigned short*)(w + 352337920);           // 512 KiB
    unsigned short* hbf1  = (unsigned short*)(w + 352862208);           // 512 KiB
    float*          cbuf  = (float*)(w + 353386496);                    //   1 MiB

    k_attn<<<BB, 512, 0, stream>>>(x, attn_w, attn_b, out0, winbf);
    k_prep_w<<<G4, 256, 0, stream>>>(Wih, Whh, bih, bhh, WihP, WhhP, biasP);
    k_gemm_xp2<<<(BB * TT / 256) * (G4 / 256), 512, 0, stream>>>(winbf, WihP, Xp);
    k_zero<<<512, 256, 0, stream>>>((float4*)hbf0);   // h(t=0)=0, c=0

    for (int t = 0; t < TT; ++t) {
        const unsigned short* hin = (t & 1) ? hbf1 : hbf0;
        unsigned short* hout      = (t & 1) ? hbf0 : hbf1;
        k_step3<<<256, 512, 0, stream>>>(t, hin, WhhP, Xp, biasP, cbuf, hout, out1);
    }
}